// Round 6
// baseline (477.914 us; speedup 1.0000x reference)
//
#include <hip/hip_runtime.h>
#include <hip/hip_bf16.h>
#include <math.h>

namespace {
constexpr int DD = 2048;          // feature dim
constexpr int EE = 64;            // experts
constexpr int KK = 8;             // top-k
constexpr int TPB = 32;           // tokens per block (one wave, two 16-row tiles)
constexpr int KSTEPS = DD / 32;   // 64
constexpr float TAU = 2e-4f;      // ambiguity gap threshold (~8 sigma of split-bf16 error)
}

typedef __attribute__((ext_vector_type(8))) short short8;   // 8 bf16 (4 VGPRs)
typedef __attribute__((ext_vector_type(4))) float f32x4;

__device__ inline void split_bf16(float v, ushort& h, ushort& l) {
    __hip_bfloat16 hb = __float2bfloat16(v);
    float hf = __bfloat162float(hb);
    __hip_bfloat16 lb = __float2bfloat16(v - hf);
    h = __builtin_bit_cast(ushort, hb);
    l = __builtin_bit_cast(ushort, lb);
}

__device__ inline void conv_tile(const float4& A, const float4& B, short8& hi, short8& lo) {
    const float f[8] = {A.x, A.y, A.z, A.w, B.x, B.y, B.z, B.w};
#pragma unroll
    for (int i = 0; i < 8; ++i) {
        ushort h, l;
        split_bf16(f[i], h, l);
        hi[i] = (short)h;
        lo[i] = (short)l;
    }
}

// Pack W_linear||W_noise into MFMA B-fragment order in workspace (verified round 5):
// ws layout (ushort): [s(64)][et(8)][hl(2)][lane(64)][i(8)]
// element: B[k][e] = W[e][k], e = et*16 + (lane&15), k = s*32 + (lane>>4)*8 + i
__global__ __launch_bounds__(256)
void prep_w(const float* __restrict__ Wl, const float* __restrict__ Wn,
            ushort* __restrict__ wsB)
{
    const int t    = blockIdx.x * 256 + threadIdx.x;    // 0..32767
    const int lane = t & 63;
    const int et   = (t >> 6) & 7;
    const int s    = t >> 9;                            // 0..63
    const int e    = et * 16 + (lane & 15);
    const int k    = s * 32 + ((lane >> 4) * 8);
    const float* src = (e < EE) ? &Wl[(long)e * DD + k] : &Wn[(long)(e - EE) * DD + k];
    const float4 f0 = *reinterpret_cast<const float4*>(src);
    const float4 f1 = *reinterpret_cast<const float4*>(src + 4);
    const float f[8] = {f0.x, f0.y, f0.z, f0.w, f1.x, f1.y, f1.z, f1.w};
    uint hw[4], lw[4];
#pragma unroll
    for (int j = 0; j < 4; ++j) {
        ushort h0, l0, h1, l1;
        split_bf16(f[2 * j], h0, l0);
        split_bf16(f[2 * j + 1], h1, l1);
        hw[j] = (uint)h0 | ((uint)h1 << 16);
        lw[j] = (uint)l0 | ((uint)l1 << 16);
    }
    const size_t chunk = ((size_t)(s * 8 + et)) * 1024;   // ushort units per (s,et)
    *reinterpret_cast<uint4*>(&wsB[chunk + lane * 8])       = make_uint4(hw[0], hw[1], hw[2], hw[3]);
    *reinterpret_cast<uint4*>(&wsB[chunk + 512 + lane * 8]) = make_uint4(lw[0], lw[1], lw[2], lw[3]);
}

__global__ __launch_bounds__(64)
void router_main(const float* __restrict__ x,
                 const float* __restrict__ noise,
                 const ushort* __restrict__ wsB,
                 const float* __restrict__ Wl, const float* __restrict__ bl,
                 const float* __restrict__ Wn, const float* __restrict__ bn,
                 float* __restrict__ out_router, float* __restrict__ out_idx)
{
    __shared__ float res[TPB][129];     // 129 = 2-way-max bank pattern for our phases
    __shared__ float tkv[TPB][KK];
    __shared__ int   tki[TPB][KK];
    __shared__ int   amb_list[TPB];
    __shared__ int   amb_count;

    const int lane = threadIdx.x;       // 0..63, single wave
    const long tok0 = (long)blockIdx.x * TPB;
    if (lane == 0) amb_count = 0;

    // ---------------- barrier-free split-bf16 MFMA GEMM ----------------
    f32x4 acc0[8], acc1[8];
#pragma unroll
    for (int i = 0; i < 8; ++i) { acc0[i] = {0.f,0.f,0.f,0.f}; acc1[i] = {0.f,0.f,0.f,0.f}; }

    // A-fragment: lane holds x[tok + (lane&15)][s*32 + (lane>>4)*8 + i], i=0..7
    const float* aptr0 = x + (tok0 + (lane & 15)) * (long)DD + ((lane >> 4) * 8);
    const float* aptr1 = aptr0 + 16 * (long)DD;
    const uint4* wp0   = reinterpret_cast<const uint4*>(wsB) + lane;

    float4 c0A = *reinterpret_cast<const float4*>(aptr0);
    float4 c0B = *reinterpret_cast<const float4*>(aptr0 + 4);
    float4 c1A = *reinterpret_cast<const float4*>(aptr1);
    float4 c1B = *reinterpret_cast<const float4*>(aptr1 + 4);

    for (int s = 0; s < KSTEPS; ++s) {
        // W fragments for this step, straight from L2-resident packed buffer
        const uint4* wp = wp0 + (size_t)s * 1024;
        uint4 w[16];
#pragma unroll
        for (int et = 0; et < 8; ++et) {
            w[et * 2]     = wp[et * 128];
            w[et * 2 + 1] = wp[et * 128 + 64];
        }
        // prefetch next A (x rows, HBM) one step ahead
        float4 p0A, p0B, p1A, p1B;
        const bool hasNext = (s + 1 < KSTEPS);
        if (hasNext) {
            const float* a0 = aptr0 + (s + 1) * 32;
            const float* a1 = aptr1 + (s + 1) * 32;
            p0A = *reinterpret_cast<const float4*>(a0);
            p0B = *reinterpret_cast<const float4*>(a0 + 4);
            p1A = *reinterpret_cast<const float4*>(a1);
            p1B = *reinterpret_cast<const float4*>(a1 + 4);
        }
        short8 a0h, a0l, a1h, a1l;
        conv_tile(c0A, c0B, a0h, a0l);
        conv_tile(c1A, c1B, a1h, a1l);
#pragma unroll
        for (int et = 0; et < 8; ++et) {
            const short8 bh = __builtin_bit_cast(short8, w[et * 2]);
            const short8 bl2 = __builtin_bit_cast(short8, w[et * 2 + 1]);
            acc0[et] = __builtin_amdgcn_mfma_f32_16x16x32_bf16(a0h, bh,  acc0[et], 0, 0, 0);
            acc1[et] = __builtin_amdgcn_mfma_f32_16x16x32_bf16(a1h, bh,  acc1[et], 0, 0, 0);
            acc0[et] = __builtin_amdgcn_mfma_f32_16x16x32_bf16(a0l, bh,  acc0[et], 0, 0, 0);
            acc1[et] = __builtin_amdgcn_mfma_f32_16x16x32_bf16(a1l, bh,  acc1[et], 0, 0, 0);
            acc0[et] = __builtin_amdgcn_mfma_f32_16x16x32_bf16(a0h, bl2, acc0[et], 0, 0, 0);
            acc1[et] = __builtin_amdgcn_mfma_f32_16x16x32_bf16(a1h, bl2, acc1[et], 0, 0, 0);
        }
        if (hasNext) { c0A = p0A; c0B = p0B; c1A = p1A; c1B = p1B; }
    }

    // ---------------- epilogue (single wave; barriers are intra-wave cheap) ----------------
    {
        // C/D layout (verified r5): col = lane&15 (expert), row = (lane>>4)*4 + reg (token)
        const int col = lane & 15;
        const int rg  = (lane >> 4) * 4;
#pragma unroll
        for (int et = 0; et < 8; ++et) {
            const int e = et * 16 + col;
            const float bias = (et < 4) ? bl[e] : bn[e - EE];
#pragma unroll
            for (int r = 0; r < 4; ++r) {
                res[rg + r][e]      = acc0[et][r] + bias;
                res[16 + rg + r][e] = acc1[et][r] + bias;
            }
        }
    }
    __syncthreads();

    // noisy = logits + noise * softplus(noise_logits); lane -> (token, 32-expert half)
    {
        const int t  = lane >> 1;
        const int e0 = (lane & 1) * 32;
        const float* nrow = &noise[(tok0 + t) * (long)EE + e0];
#pragma unroll 8
        for (int j = 0; j < 32; ++j) {
            const float z  = res[t][EE + e0 + j];
            const float sp = fmaxf(z, 0.f) + log1pf(expf(-fabsf(z)));
            res[t][e0 + j] = res[t][e0 + j] + nrow[j] * sp;
        }
    }
    __syncthreads();

    // top-9 extraction (lanes 0..31, one token each); strict > keeps lowest index on ties
    if (lane < TPB) {
        const int t = lane;
        float lv[9]; int li[9];
#pragma unroll
        for (int k = 0; k < 9; ++k) {
            float best = -INFINITY;
            int bi = 0;
#pragma unroll 4
            for (int e = 0; e < EE; ++e) {
                const float v = res[t][e];
                if (v > best) { best = v; bi = e; }
            }
            res[t][bi] = -INFINITY;
            lv[k] = best; li[k] = bi;
        }
        bool amb = false;
#pragma unroll
        for (int k = 0; k < 8; ++k) amb |= (lv[k] - lv[k + 1] < TAU);
        const float m = lv[0];
        float p[KK];
        float sm = 0.f;
#pragma unroll
        for (int k = 0; k < KK; ++k) { p[k] = expf(lv[k] - m); sm += p[k]; }
        const float inv = 1.f / sm;
#pragma unroll
        for (int k = 0; k < KK; ++k) { tkv[t][k] = p[k] * inv; tki[t][k] = li[k]; }
        if (amb) { const int pos = atomicAdd(&amb_count, 1); amb_list[pos] = t; }
    }
    __syncthreads();

    // fp64 recompute of ambiguous tokens (near-tie -> split-bf16 ordering unsafe)
    const int namb = amb_count;
    for (int a = 0; a < namb; ++a) {
        const int t = amb_list[a];
        const float* xr = &x[(tok0 + t) * (long)DD];
        double vlin, vnoi;
#pragma unroll
        for (int pass = 0; pass < 2; ++pass) {
            const float* wr = (pass == 0) ? &Wl[(long)lane * DD] : &Wn[(long)lane * DD];
            double s0 = 0.0, s1 = 0.0, s2 = 0.0, s3 = 0.0;
            for (int k = 0; k < DD; k += 4) {
                const float4 xv = *reinterpret_cast<const float4*>(&xr[k]);
                const float4 wv = *reinterpret_cast<const float4*>(&wr[k]);
                s0 = fma((double)xv.x, (double)wv.x, s0);
                s1 = fma((double)xv.y, (double)wv.y, s1);
                s2 = fma((double)xv.z, (double)wv.z, s2);
                s3 = fma((double)xv.w, (double)wv.w, s3);
            }
            const double d = (s0 + s1) + (s2 + s3);
            if (pass == 0) vlin = d + (double)bl[lane];
            else           vnoi = d + (double)bn[lane];
        }
        {
            const double sp = fmax(vnoi, 0.0) + log1p(exp(-fabs(vnoi)));
            double val = vlin + (double)noise[(tok0 + t) * (long)EE + lane] * sp;
            int    idx = lane;
            double sel[KK]; int sidx[KK];
#pragma unroll
            for (int k = 0; k < KK; ++k) {
                double mv = val; int mi = idx;
#pragma unroll
                for (int m = 1; m < 64; m <<= 1) {
                    const double ov = __shfl_xor(mv, m, 64);
                    const int    oi = __shfl_xor(mi, m, 64);
                    if (ov > mv || (ov == mv && oi < mi)) { mv = ov; mi = oi; }
                }
                sel[k] = mv; sidx[k] = mi;
                if (idx == mi) val = -INFINITY;
            }
            if (lane == 0) {
                const double mx = sel[0];
                double p[KK]; double sm = 0.0;
#pragma unroll
                for (int k = 0; k < KK; ++k) { p[k] = exp(sel[k] - mx); sm += p[k]; }
                const double inv = 1.0 / sm;
#pragma unroll
                for (int k = 0; k < KK; ++k) {
                    tkv[t][k] = (float)(p[k] * inv);
                    tki[t][k] = sidx[k];
                }
            }
        }
        __syncthreads();
    }

    // router output: compare-select scatter, float4 stores
    {
        const int t  = lane >> 1;
        const int e0 = (lane & 1) * 32;
        int   ki[KK];
        float kv[KK];
#pragma unroll
        for (int k = 0; k < KK; ++k) { ki[k] = tki[t][k]; kv[k] = tkv[t][k]; }
        float v[32];
#pragma unroll
        for (int j = 0; j < 32; ++j) {
            float val = 0.f;
#pragma unroll
            for (int k = 0; k < KK; ++k)
                val = (ki[k] == e0 + j) ? kv[k] : val;
            v[j] = val;
        }
        float* dst = &out_router[(tok0 + t) * (long)EE + e0];
#pragma unroll
        for (int q = 0; q < 8; ++q)
            *reinterpret_cast<float4*>(dst + q * 4) = make_float4(v[q*4], v[q*4+1], v[q*4+2], v[q*4+3]);
    }
    // indices output, written as float32 values (whole d_out read as f32 by harness)
    {
        const int t  = lane >> 1;
        const int k0 = (lane & 1) * 4;
        const float4 iv = make_float4((float)tki[t][k0],     (float)tki[t][k0 + 1],
                                      (float)tki[t][k0 + 2], (float)tki[t][k0 + 3]);
        *reinterpret_cast<float4*>(&out_idx[(tok0 + t) * (long)KK + k0]) = iv;
    }
}

extern "C" void kernel_launch(void* const* d_in, const int* in_sizes, int n_in,
                              void* d_out, int out_size, void* d_ws, size_t ws_size,
                              hipStream_t stream) {
    const float* x     = (const float*)d_in[0];
    const float* noise = (const float*)d_in[1];
    const float* Wl    = (const float*)d_in[2];
    const float* bl    = (const float*)d_in[3];
    const float* Wn    = (const float*)d_in[4];
    const float* bn    = (const float*)d_in[5];

    const int M = in_sizes[0] / DD;            // B*S = 32768
    float* out_router = (float*)d_out;
    float* out_idx    = (float*)d_out + (long)M * EE;
    ushort* wsB = (ushort*)d_ws;               // 1 MiB fragment-packed W hi/lo

    hipLaunchKernelGGL(prep_w, dim3(128), dim3(256), 0, stream, Wl, Wn, wsB);
    hipLaunchKernelGGL(router_main, dim3(M / TPB), dim3(64), 0, stream,
                       x, noise, wsB, Wl, bl, Wn, bn, out_router, out_idx);
}

// Round 7
// 375.798 us; speedup vs baseline: 1.2717x; 1.2717x over previous
//
#include <hip/hip_runtime.h>
#include <hip/hip_bf16.h>
#include <math.h>

namespace {
constexpr int DD = 2048;          // feature dim
constexpr int EE = 64;            // experts
constexpr int KK = 8;             // top-k
constexpr int TPB = 64;           // tokens per block
constexpr int BK = 32;            // K-step
constexpr int NTH = 512;          // 8 waves
constexpr int KSTEPS = DD / BK;   // 64
constexpr float TAU = 2e-4f;      // ambiguity gap threshold (~8 sigma of split-bf16 error)
}

typedef __attribute__((ext_vector_type(8))) short short8;   // 8 bf16 (4 VGPRs)
typedef __attribute__((ext_vector_type(4))) float f32x4;

__device__ inline void split_bf16(float v, ushort& h, ushort& l) {
    __hip_bfloat16 hb = __float2bfloat16(v);
    float hf = __bfloat162float(hb);
    __hip_bfloat16 lb = __float2bfloat16(v - hf);
    h = __builtin_bit_cast(ushort, hb);
    l = __builtin_bit_cast(ushort, lb);
}

__device__ inline void conv_tile(const float4& A, const float4& B, short8& hi, short8& lo) {
    const float f[8] = {A.x, A.y, A.z, A.w, B.x, B.y, B.z, B.w};
#pragma unroll
    for (int i = 0; i < 8; ++i) {
        ushort h, l;
        split_bf16(f[i], h, l);
        hi[i] = (short)h;
        lo[i] = (short)l;
    }
}

__device__ inline void gload_lds16(const void* g, void* l) {
    __builtin_amdgcn_global_load_lds(
        (const __attribute__((address_space(1))) unsigned int*)g,
        (__attribute__((address_space(3))) unsigned int*)l,
        16, 0, 0);
}

// Pack W_linear||W_noise into MFMA B-fragment order in workspace (verified round 5):
// ws layout (ushort): [s(64)][et(8)][hl(2)][lane(64)][i(8)]
// element: B[k][e] = W[e][k], e = et*16 + (lane&15), k = s*32 + (lane>>4)*8 + i
__global__ __launch_bounds__(256)
void prep_w(const float* __restrict__ Wl, const float* __restrict__ Wn,
            ushort* __restrict__ wsB)
{
    const int t    = blockIdx.x * 256 + threadIdx.x;    // 0..32767
    const int lane = t & 63;
    const int et   = (t >> 6) & 7;
    const int s    = t >> 9;                            // 0..63
    const int e    = et * 16 + (lane & 15);
    const int k    = s * 32 + ((lane >> 4) * 8);
    const float* src = (e < EE) ? &Wl[(long)e * DD + k] : &Wn[(long)(e - EE) * DD + k];
    const float4 f0 = *reinterpret_cast<const float4*>(src);
    const float4 f1 = *reinterpret_cast<const float4*>(src + 4);
    const float f[8] = {f0.x, f0.y, f0.z, f0.w, f1.x, f1.y, f1.z, f1.w};
    uint hw[4], lw[4];
#pragma unroll
    for (int j = 0; j < 4; ++j) {
        ushort h0, l0, h1, l1;
        split_bf16(f[2 * j], h0, l0);
        split_bf16(f[2 * j + 1], h1, l1);
        hw[j] = (uint)h0 | ((uint)h1 << 16);
        lw[j] = (uint)l0 | ((uint)l1 << 16);
    }
    const size_t chunk = ((size_t)(s * 8 + et)) * 1024;   // ushort units per (s,et)
    *reinterpret_cast<uint4*>(&wsB[chunk + lane * 8])       = make_uint4(hw[0], hw[1], hw[2], hw[3]);
    *reinterpret_cast<uint4*>(&wsB[chunk + 512 + lane * 8]) = make_uint4(lw[0], lw[1], lw[2], lw[3]);
}

__global__ __launch_bounds__(NTH, 4)
void router_main(const float* __restrict__ x,
                 const float* __restrict__ noise,
                 const ushort* __restrict__ wsB,
                 const float* __restrict__ Wl, const float* __restrict__ bl,
                 const float* __restrict__ Wn, const float* __restrict__ bn,
                 float* __restrict__ out_router, float* __restrict__ out_idx)
{
    __shared__ __align__(16) float xsb[2][TPB * BK];   // swizzled x tile, dbuf (16 KB)
    __shared__ float res[TPB][129];                    // logits | noise_logits -> noisy
    __shared__ float tkv[TPB][KK];
    __shared__ int   tki[TPB][KK];
    __shared__ int   amb_list[TPB];
    __shared__ int   amb_count;
    __shared__ double part[256];
    __shared__ double dots[128];

    const int tid  = threadIdx.x;
    const int lane = tid & 63;
    const int w    = tid >> 6;          // wave 0..7
    const int wm   = w >> 1;            // token group 0..3 (16 tokens each)
    const int wn   = w & 1;             // expert half (et 0..3 | 4..7)
    const long tok0 = (long)blockIdx.x * TPB;
    if (tid == 0) amb_count = 0;

    // staging coords: thread -> (row t, 16B unit q), source column = q ^ (t&7)
    const int st = tid >> 3;            // 0..63 token row
    const int sq = tid & 7;             // 16B unit
    const float* gsrc0 = x + (tok0 + st) * (long)DD + ((sq ^ (st & 7)) << 2);
    float* ldst0 = &xsb[0][w * 256];    // wave-uniform base; HW adds lane*16B
    float* ldst1 = &xsb[1][w * 256];

    // A-fragment read coords
    const int arow = wm * 16 + (lane & 15);
    const int aq0  = ((lane >> 4) * 2) ^ (arow & 7);
    const int aq1  = ((lane >> 4) * 2 + 1) ^ (arow & 7);
    const float* abase = &xsb[0][arow * BK];

    const uint4* wp = reinterpret_cast<const uint4*>(wsB) + lane;

    f32x4 acc[4];
#pragma unroll
    for (int i = 0; i < 4; ++i) acc[i] = {0.f, 0.f, 0.f, 0.f};

    // prologue: stage step 0
    gload_lds16(gsrc0, ldst0);
    __syncthreads();

    for (int s = 0; s < KSTEPS; ++s) {
        const int cur = s & 1;
        if (s + 1 < KSTEPS)            // stage next tile (async, drained at barrier)
            gload_lds16(gsrc0 + (s + 1) * BK, cur ? ldst0 : ldst1);

        // W fragments for this step (L2-resident)
        uint4 wh[4], wl[4];
#pragma unroll
        for (int etl = 0; etl < 4; ++etl) {
            const size_t base = ((size_t)(s * 8 + wn * 4 + etl)) * 128;
            wh[etl] = wp[base];
            wl[etl] = wp[base + 64];
        }

        // A fragment from swizzled LDS
        const float* ab = abase + cur * (TPB * BK);
        const float4 f0 = *reinterpret_cast<const float4*>(ab + aq0 * 4);
        const float4 f1 = *reinterpret_cast<const float4*>(ab + aq1 * 4);
        short8 ahi, alo;
        conv_tile(f0, f1, ahi, alo);

#pragma unroll
        for (int etl = 0; etl < 4; ++etl) {
            const short8 bh = __builtin_bit_cast(short8, wh[etl]);
            const short8 bl2 = __builtin_bit_cast(short8, wl[etl]);
            acc[etl] = __builtin_amdgcn_mfma_f32_16x16x32_bf16(ahi, bh,  acc[etl], 0, 0, 0);
            acc[etl] = __builtin_amdgcn_mfma_f32_16x16x32_bf16(alo, bh,  acc[etl], 0, 0, 0);
            acc[etl] = __builtin_amdgcn_mfma_f32_16x16x32_bf16(ahi, bl2, acc[etl], 0, 0, 0);
        }
        __syncthreads();
    }

    // ---------------- epilogue ----------------
    {
        // C/D layout (verified r5): col = lane&15 (expert), row = (lane>>4)*4 + reg (token)
        const int col = lane & 15;
        const int rg  = (lane >> 4) * 4;
#pragma unroll
        for (int etl = 0; etl < 4; ++etl) {
            const int e = (wn * 4 + etl) * 16 + col;
            const float bias = (e < EE) ? bl[e] : bn[e - EE];
#pragma unroll
            for (int r = 0; r < 4; ++r)
                res[wm * 16 + rg + r][e] = acc[etl][r] + bias;
        }
    }
    __syncthreads();

    // noisy = logits + noise * softplus(noise_logits); thread -> (token, 8 experts)
    {
        const int t  = tid >> 3;
        const int j0 = (tid & 7) * 8;
        const float4 n0 = *reinterpret_cast<const float4*>(&noise[(tok0 + t) * (long)EE + j0]);
        const float4 n1 = *reinterpret_cast<const float4*>(&noise[(tok0 + t) * (long)EE + j0 + 4]);
        const float nv[8] = {n0.x, n0.y, n0.z, n0.w, n1.x, n1.y, n1.z, n1.w};
#pragma unroll
        for (int j = 0; j < 8; ++j) {
            const float z  = res[t][EE + j0 + j];
            const float sp = fmaxf(z, 0.f) + log1pf(expf(-fabsf(z)));
            res[t][j0 + j] = res[t][j0 + j] + nv[j] * sp;
        }
    }
    __syncthreads();

    // top-9 extraction (threads 0..63); strict > keeps lowest index on ties
    if (tid < TPB) {
        const int t = tid;
        float lv[9]; int li[9];
#pragma unroll
        for (int k = 0; k < 9; ++k) {
            float best = -INFINITY;
            int bi = 0;
#pragma unroll 4
            for (int e = 0; e < EE; ++e) {
                const float v = res[t][e];
                if (v > best) { best = v; bi = e; }
            }
            res[t][bi] = -INFINITY;
            lv[k] = best; li[k] = bi;
        }
        bool amb = false;
#pragma unroll
        for (int k = 0; k < 8; ++k) amb |= (lv[k] - lv[k + 1] < TAU);
        const float m = lv[0];
        float p[KK];
        float sm = 0.f;
#pragma unroll
        for (int k = 0; k < KK; ++k) { p[k] = expf(lv[k] - m); sm += p[k]; }
        const float inv = 1.f / sm;
#pragma unroll
        for (int k = 0; k < KK; ++k) { tkv[t][k] = p[k] * inv; tki[t][k] = li[k]; }
        if (amb) { const int pos = atomicAdd(&amb_count, 1); amb_list[pos] = t; }
    }
    __syncthreads();

    // fp64 recompute of ambiguous tokens (near-tie -> split-bf16 ordering unsafe)
    const int namb = amb_count;
    for (int a = 0; a < namb; ++a) {
        const int t = amb_list[a];
        if (tid < 256) {
            const int e  = tid >> 1;
            const int kb = (tid & 1) * (DD / 2);
            const float* xr = &x[(tok0 + t) * (long)DD + kb];
            const float* wr = (e < EE) ? &Wl[(long)e * DD + kb]
                                       : &Wn[(long)(e - EE) * DD + kb];
            double a2 = 0.0;
            for (int k = 0; k < DD / 2; k += 4) {
                const float4 xv = *reinterpret_cast<const float4*>(&xr[k]);
                const float4 wv = *reinterpret_cast<const float4*>(&wr[k]);
                a2 = fma((double)xv.x, (double)wv.x, a2);
                a2 = fma((double)xv.y, (double)wv.y, a2);
                a2 = fma((double)xv.z, (double)wv.z, a2);
                a2 = fma((double)xv.w, (double)wv.w, a2);
            }
            part[tid] = a2;
        }
        __syncthreads();
        if (tid < 128) dots[tid] = part[2 * tid] + part[2 * tid + 1];
        __syncthreads();
        if (tid < EE) {   // wave 0: fp64 noisy + butterfly top-8 + fp64 softmax
            const double v  = dots[tid] + (double)bl[tid];
            const double z  = dots[EE + tid] + (double)bn[tid];
            const double sp = fmax(z, 0.0) + log1p(exp(-fabs(z)));
            double val = v + (double)noise[(tok0 + t) * (long)EE + tid] * sp;
            int    idx = tid;
            double sel[KK]; int sidx[KK];
#pragma unroll
            for (int k = 0; k < KK; ++k) {
                double mv = val; int mi = idx;
#pragma unroll
                for (int m = 1; m < 64; m <<= 1) {
                    const double ov = __shfl_xor(mv, m, 64);
                    const int    oi = __shfl_xor(mi, m, 64);
                    if (ov > mv || (ov == mv && oi < mi)) { mv = ov; mi = oi; }
                }
                sel[k] = mv; sidx[k] = mi;
                if (idx == mi) val = -INFINITY;
            }
            if (tid == 0) {
                const double mx = sel[0];
                double p[KK]; double sm = 0.0;
#pragma unroll
                for (int k = 0; k < KK; ++k) { p[k] = exp(sel[k] - mx); sm += p[k]; }
                const double inv = 1.0 / sm;
#pragma unroll
                for (int k = 0; k < KK; ++k) {
                    tkv[t][k] = (float)(p[k] * inv);
                    tki[t][k] = sidx[k];
                }
            }
        }
        __syncthreads();
    }

    // router output: compare-select scatter, two float4 stores per thread
    {
        const int t  = tid >> 3;
        const int e0 = (tid & 7) * 8;
        int   ki[KK];
        float kv[KK];
#pragma unroll
        for (int k = 0; k < KK; ++k) { ki[k] = tki[t][k]; kv[k] = tkv[t][k]; }
        float v[8];
#pragma unroll
        for (int j = 0; j < 8; ++j) {
            float val = 0.f;
#pragma unroll
            for (int k = 0; k < KK; ++k)
                val = (ki[k] == e0 + j) ? kv[k] : val;
            v[j] = val;
        }
        float* dst = &out_router[(tok0 + t) * (long)EE + e0];
        *reinterpret_cast<float4*>(dst)     = make_float4(v[0], v[1], v[2], v[3]);
        *reinterpret_cast<float4*>(dst + 4) = make_float4(v[4], v[5], v[6], v[7]);
    }
    // indices output, written as float32 values (whole d_out read as f32 by harness)
    {
        const int t = tid >> 3;
        const int k = tid & 7;
        out_idx[(tok0 + t) * (long)KK + k] = (float)tki[t][k];
    }
}

extern "C" void kernel_launch(void* const* d_in, const int* in_sizes, int n_in,
                              void* d_out, int out_size, void* d_ws, size_t ws_size,
                              hipStream_t stream) {
    const float* x     = (const float*)d_in[0];
    const float* noise = (const float*)d_in[1];
    const float* Wl    = (const float*)d_in[2];
    const float* bl    = (const float*)d_in[3];
    const float* Wn    = (const float*)d_in[4];
    const float* bn    = (const float*)d_in[5];

    const int M = in_sizes[0] / DD;            // B*S = 32768
    float* out_router = (float*)d_out;
    float* out_idx    = (float*)d_out + (long)M * EE;
    ushort* wsB = (ushort*)d_ws;               // 1 MiB fragment-packed W hi/lo

    hipLaunchKernelGGL(prep_w, dim3(128), dim3(256), 0, stream, Wl, Wn, wsB);
    hipLaunchKernelGGL(router_main, dim3(M / TPB), dim3(NTH), 0, stream,
                       x, noise, wsB, Wl, bl, Wn, bn, out_router, out_idx);
}

// Round 8
// 374.296 us; speedup vs baseline: 1.2768x; 1.0040x over previous
//
#include <hip/hip_runtime.h>
#include <hip/hip_bf16.h>
#include <math.h>

namespace {
constexpr int DD = 2048;          // feature dim
constexpr int EE = 64;            // experts
constexpr int KK = 8;             // top-k
constexpr int TPB = 64;           // tokens per block
constexpr int BK = 64;            // K per step
constexpr int NTH = 256;          // 4 waves
constexpr int NSTEP = DD / BK;    // 32
constexpr int XBYTES = 16384;     // x region: 64 rows x 256B (bf16 hi|lo)
constexpr int WBYTES = 32768;     // W region: 32 KB per step
constexpr float TAU = 2e-4f;      // ambiguity gap threshold (>> split-bf16 error ~1e-5)
}

typedef __attribute__((ext_vector_type(8))) short short8;   // 8 bf16 (4 VGPRs)
typedef __attribute__((ext_vector_type(4))) float f32x4;

#define RES(t, e) res[(t) * 129 + (e)]

__device__ inline void split_bf16(float v, ushort& h, ushort& l) {
    __hip_bfloat16 hb = __float2bfloat16(v);
    float hf = __bfloat162float(hb);
    __hip_bfloat16 lb = __float2bfloat16(v - hf);
    h = __builtin_bit_cast(ushort, hb);
    l = __builtin_bit_cast(ushort, lb);
}

__device__ inline void gload_lds16(const void* g, void* l) {
    __builtin_amdgcn_global_load_lds(
        (const __attribute__((address_space(1))) unsigned int*)g,
        (__attribute__((address_space(3))) unsigned int*)l,
        16, 0, 0);
}

// Pack W_linear||W_noise into MFMA B-fragment order (verified round 5):
// ushort layout [s32(64)][et(8)][hl(2)][lane(64)][i(8)]
// element: B[k][e] = W[e][k], e = et*16 + (lane&15), k = s32*32 + (lane>>4)*8 + i
__global__ __launch_bounds__(256)
void prep_w(const float* __restrict__ Wl, const float* __restrict__ Wn,
            ushort* __restrict__ wsB)
{
    const int t    = blockIdx.x * 256 + threadIdx.x;    // 0..32767
    const int lane = t & 63;
    const int et   = (t >> 6) & 7;
    const int s    = t >> 9;                            // 0..63
    const int e    = et * 16 + (lane & 15);
    const int k    = s * 32 + ((lane >> 4) * 8);
    const float* src = (e < EE) ? &Wl[(long)e * DD + k] : &Wn[(long)(e - EE) * DD + k];
    const float4 f0 = *reinterpret_cast<const float4*>(src);
    const float4 f1 = *reinterpret_cast<const float4*>(src + 4);
    const float f[8] = {f0.x, f0.y, f0.z, f0.w, f1.x, f1.y, f1.z, f1.w};
    uint hw[4], lw[4];
#pragma unroll
    for (int j = 0; j < 4; ++j) {
        ushort h0, l0, h1, l1;
        split_bf16(f[2 * j], h0, l0);
        split_bf16(f[2 * j + 1], h1, l1);
        hw[j] = (uint)h0 | ((uint)h1 << 16);
        lw[j] = (uint)l0 | ((uint)l1 << 16);
    }
    const size_t chunk = ((size_t)(s * 8 + et)) * 1024;   // ushort units per (s,et)
    *reinterpret_cast<uint4*>(&wsB[chunk + lane * 8])       = make_uint4(hw[0], hw[1], hw[2], hw[3]);
    *reinterpret_cast<uint4*>(&wsB[chunk + 512 + lane * 8]) = make_uint4(lw[0], lw[1], lw[2], lw[3]);
}

__global__ __launch_bounds__(NTH, 2)
void router_main(const float* __restrict__ x,
                 const float* __restrict__ noise,
                 const ushort* __restrict__ wsB,
                 const float* __restrict__ Wl, const float* __restrict__ bl,
                 const float* __restrict__ Wn, const float* __restrict__ bn,
                 float* __restrict__ out_router, float* __restrict__ out_idx)
{
    // stage region: [0,16K) x bf16 hi/lo, [16K,48K) W step slice; res aliases post-loop
    __shared__ __align__(16) unsigned char smem[XBYTES + WBYTES];
    __shared__ float tkv[TPB][KK];
    __shared__ int   tki[TPB][KK];
    __shared__ int   amb_list[TPB];
    __shared__ int   amb_count;
    __shared__ double part[256];
    __shared__ double dots[128];

    const int tid  = threadIdx.x;
    const int lane = tid & 63;
    const int w    = tid >> 6;           // wave 0..3
    const int mh   = w >> 1;             // token half (32 tokens)
    const int eh   = w & 1;              // et half (4 et tiles)
    const long tok0 = (long)blockIdx.x * TPB;
    const int phase = blockIdx.x & (NSTEP - 1);   // K-rotation (channel decorrelation)
    if (tid == 0) amb_count = 0;

    // x stage mapping: thread -> (row sr, 16-float chunk sp)
    const int sr = tid >> 2;
    const int sp = tid & 3;
    const float* xrow = x + (tok0 + sr) * (long)DD + sp * 16;

    f32x4 acc[2][4];
#pragma unroll
    for (int mi = 0; mi < 2; ++mi)
#pragma unroll
        for (int e = 0; e < 4; ++e) acc[mi][e] = {0.f, 0.f, 0.f, 0.f};

    // prologue: x for step 0 into registers
    float4 xr0, xr1, xr2, xr3;
    {
        const float* p = xrow + (size_t)phase * BK;
        xr0 = *reinterpret_cast<const float4*>(p);
        xr1 = *reinterpret_cast<const float4*>(p + 4);
        xr2 = *reinterpret_cast<const float4*>(p + 8);
        xr3 = *reinterpret_cast<const float4*>(p + 12);
    }

    for (int s = 0; s < NSTEP; ++s) {
        const int se = (s + phase) & (NSTEP - 1);
        // ---- convert prefetched x -> bf16 hi/lo, ds_write (swizzled) ----
        {
            const float fv[16] = {xr0.x, xr0.y, xr0.z, xr0.w, xr1.x, xr1.y, xr1.z, xr1.w,
                                  xr2.x, xr2.y, xr2.z, xr2.w, xr3.x, xr3.y, xr3.z, xr3.w};
            const int swz = sr & 15;
#pragma unroll
            for (int oo = 0; oo < 2; ++oo) {
                const int o  = sp * 2 + oo;                      // octet 0..7 (8 floats)
                const int qh = ((o >> 2) * 8) + ((o & 3) * 2);   // hi cell q
                uint hw[4], lw[4];
#pragma unroll
                for (int j = 0; j < 4; ++j) {
                    ushort h0, l0, h1, l1;
                    split_bf16(fv[oo * 8 + 2 * j], h0, l0);
                    split_bf16(fv[oo * 8 + 2 * j + 1], h1, l1);
                    hw[j] = (uint)h0 | ((uint)h1 << 16);
                    lw[j] = (uint)l0 | ((uint)l1 << 16);
                }
                *reinterpret_cast<uint4*>(smem + sr * 256 + ((qh ^ swz) * 16)) =
                    make_uint4(hw[0], hw[1], hw[2], hw[3]);
                *reinterpret_cast<uint4*>(smem + sr * 256 + (((qh + 1) ^ swz) * 16)) =
                    make_uint4(lw[0], lw[1], lw[2], lw[3]);
            }
        }
        // ---- stage W step slice (32 KB, fire-and-forget into LDS) ----
        {
            const char* wsrc = reinterpret_cast<const char*>(wsB) + (size_t)se * WBYTES;
#pragma unroll
            for (int j = 0; j < 8; ++j) {
                gload_lds16(wsrc + (size_t)(j * 256 + tid) * 16,
                            smem + XBYTES + (j * 256 + w * 64) * 16);
            }
        }
        __syncthreads();   // drains vmcnt (W arrived) + lgkm (x written)

        // ---- prefetch next x into registers (hides under compute) ----
        if (s + 1 < NSTEP) {
            const int kn = ((s + 1 + phase) & (NSTEP - 1)) * BK;
            const float* p = xrow + kn;
            xr0 = *reinterpret_cast<const float4*>(p);
            xr1 = *reinterpret_cast<const float4*>(p + 4);
            xr2 = *reinterpret_cast<const float4*>(p + 8);
            xr3 = *reinterpret_cast<const float4*>(p + 12);
        }

        // ---- compute: all operands via LDS ----
#pragma unroll
        for (int c = 0; c < 2; ++c) {
            const int rb0 = mh * 32 + (lane & 15);
            const int rb1 = rb0 + 16;
            const int qb  = c * 8 + ((lane >> 4) * 2);
            const int sw0 = rb0 & 15;                 // == lane&15 for both rows
            const short8 ah0 = *reinterpret_cast<const short8*>(smem + rb0 * 256 + ((qb ^ sw0) * 16));
            const short8 al0 = *reinterpret_cast<const short8*>(smem + rb0 * 256 + (((qb + 1) ^ sw0) * 16));
            const short8 ah1 = *reinterpret_cast<const short8*>(smem + rb1 * 256 + ((qb ^ sw0) * 16));
            const short8 al1 = *reinterpret_cast<const short8*>(smem + rb1 * 256 + (((qb + 1) ^ sw0) * 16));
#pragma unroll
            for (int etl = 0; etl < 4; ++etl) {
                const int et = eh * 4 + etl;
                const unsigned char* wb = smem + XBYTES + ((c * 8 + et) * 2) * 1024 + lane * 16;
                const short8 bh  = *reinterpret_cast<const short8*>(wb);
                const short8 bl2 = *reinterpret_cast<const short8*>(wb + 1024);
                acc[0][etl] = __builtin_amdgcn_mfma_f32_16x16x32_bf16(ah0, bh,  acc[0][etl], 0, 0, 0);
                acc[1][etl] = __builtin_amdgcn_mfma_f32_16x16x32_bf16(ah1, bh,  acc[1][etl], 0, 0, 0);
                acc[0][etl] = __builtin_amdgcn_mfma_f32_16x16x32_bf16(al0, bh,  acc[0][etl], 0, 0, 0);
                acc[1][etl] = __builtin_amdgcn_mfma_f32_16x16x32_bf16(al1, bh,  acc[1][etl], 0, 0, 0);
                acc[0][etl] = __builtin_amdgcn_mfma_f32_16x16x32_bf16(ah0, bl2, acc[0][etl], 0, 0, 0);
                acc[1][etl] = __builtin_amdgcn_mfma_f32_16x16x32_bf16(ah1, bl2, acc[1][etl], 0, 0, 0);
            }
        }
        __syncthreads();   // readers done before next overwrite
    }

    // ---------------- epilogue (res aliases stage region) ----------------
    float* res = reinterpret_cast<float*>(smem);   // [64][129]
    {
        // C/D layout (verified r5): col = lane&15 (expert), row = (lane>>4)*4 + reg
        const int col = lane & 15;
        const int rg  = (lane >> 4) * 4;
#pragma unroll
        for (int mi = 0; mi < 2; ++mi)
#pragma unroll
            for (int etl = 0; etl < 4; ++etl) {
                const int e = (eh * 4 + etl) * 16 + col;
                const float bias = (e < EE) ? bl[e] : bn[e - EE];
#pragma unroll
                for (int r = 0; r < 4; ++r)
                    RES(mh * 32 + mi * 16 + rg + r, e) = acc[mi][etl][r] + bias;
            }
    }
    __syncthreads();

    // noisy = logits + noise * softplus(noise_logits)
    {
        const int t  = tid >> 2;
        const int e0 = (tid & 3) * 16;
        const float* nrow = &noise[(tok0 + t) * (long)EE];
#pragma unroll 4
        for (int j = 0; j < 16; ++j) {
            const int e = e0 + j;
            const float z  = RES(t, EE + e);
            const float sp = fmaxf(z, 0.f) + log1pf(expf(-fabsf(z)));
            RES(t, e) = RES(t, e) + nrow[e] * sp;
        }
    }
    __syncthreads();

    // top-9 extraction per token (threads 0..63); strict > keeps lowest index on ties
    if (tid < TPB) {
        const int t = tid;
        float lv[9]; int li[9];
#pragma unroll
        for (int k = 0; k < 9; ++k) {
            float best = -INFINITY;
            int bi = 0;
#pragma unroll 4
            for (int e = 0; e < EE; ++e) {
                const float v = RES(t, e);
                if (v > best) { best = v; bi = e; }
            }
            RES(t, bi) = -INFINITY;
            lv[k] = best; li[k] = bi;
        }
        bool amb = false;
#pragma unroll
        for (int k = 0; k < 8; ++k) amb |= (lv[k] - lv[k + 1] < TAU);
        const float m = lv[0];
        float p[KK];
        float sm = 0.f;
#pragma unroll
        for (int k = 0; k < KK; ++k) { p[k] = expf(lv[k] - m); sm += p[k]; }
        const float inv = 1.f / sm;
#pragma unroll
        for (int k = 0; k < KK; ++k) { tkv[t][k] = p[k] * inv; tki[t][k] = li[k]; }
        if (amb) { const int pos = atomicAdd(&amb_count, 1); amb_list[pos] = t; }
    }
    __syncthreads();

    // fp64 recompute of ambiguous tokens (near-tie -> split-bf16 ordering unsafe)
    const int namb = amb_count;
    for (int a = 0; a < namb; ++a) {
        const int t = amb_list[a];
        {
            const int e  = tid >> 1;
            const int kb = (tid & 1) * (DD / 2);
            const float* xr = &x[(tok0 + t) * (long)DD + kb];
            const float* wr = (e < EE) ? &Wl[(long)e * DD + kb]
                                       : &Wn[(long)(e - EE) * DD + kb];
            double a2 = 0.0;
            for (int k = 0; k < DD / 2; k += 4) {
                const float4 xv = *reinterpret_cast<const float4*>(&xr[k]);
                const float4 wv = *reinterpret_cast<const float4*>(&wr[k]);
                a2 = fma((double)xv.x, (double)wv.x, a2);
                a2 = fma((double)xv.y, (double)wv.y, a2);
                a2 = fma((double)xv.z, (double)wv.z, a2);
                a2 = fma((double)xv.w, (double)wv.w, a2);
            }
            part[tid] = a2;
        }
        __syncthreads();
        if (tid < 128) dots[tid] = part[2 * tid] + part[2 * tid + 1];
        __syncthreads();
        if (tid < EE) {   // wave 0: fp64 noisy + butterfly top-8 + fp64 softmax
            const double v  = dots[tid] + (double)bl[tid];
            const double z  = dots[EE + tid] + (double)bn[tid];
            const double sp = fmax(z, 0.0) + log1p(exp(-fabs(z)));
            double val = v + (double)noise[(tok0 + t) * (long)EE + tid] * sp;
            int    idx = tid;
            double sel[KK]; int sidx[KK];
#pragma unroll
            for (int k = 0; k < KK; ++k) {
                double mv = val; int mi = idx;
#pragma unroll
                for (int m = 1; m < 64; m <<= 1) {
                    const double ov = __shfl_xor(mv, m, 64);
                    const int    oi = __shfl_xor(mi, m, 64);
                    if (ov > mv || (ov == mv && oi < mi)) { mv = ov; mi = oi; }
                }
                sel[k] = mv; sidx[k] = mi;
                if (idx == mi) val = -INFINITY;
            }
            if (tid == 0) {
                const double mx = sel[0];
                double p[KK]; double sm = 0.0;
#pragma unroll
                for (int k = 0; k < KK; ++k) { p[k] = exp(sel[k] - mx); sm += p[k]; }
                const double inv = 1.0 / sm;
#pragma unroll
                for (int k = 0; k < KK; ++k) {
                    tkv[t][k] = (float)(p[k] * inv);
                    tki[t][k] = sidx[k];
                }
            }
        }
        __syncthreads();
    }

    // router output: compare-select scatter, coalesced float4 stores
    {
        const int t  = tid >> 2;
        const int e0 = (tid & 3) * 16;
        int   ki[KK];
        float kv[KK];
#pragma unroll
        for (int k = 0; k < KK; ++k) { ki[k] = tki[t][k]; kv[k] = tkv[t][k]; }
        float4 v[4];
        float* vf = reinterpret_cast<float*>(v);
#pragma unroll
        for (int j = 0; j < 16; ++j) {
            float val = 0.f;
#pragma unroll
            for (int k = 0; k < KK; ++k)
                val = (ki[k] == e0 + j) ? kv[k] : val;
            vf[j] = val;
        }
        float4* dst = reinterpret_cast<float4*>(&out_router[(tok0 + t) * (long)EE + e0]);
#pragma unroll
        for (int q = 0; q < 4; ++q) dst[q] = v[q];
    }
    // indices output, written as float32 values (whole d_out read as f32 by harness)
    {
        const int f = tid * 2;
        const int t = f >> 3;
        const int k0i = f & 7;
        out_idx[(tok0 + t) * (long)KK + k0i]     = (float)tki[t][k0i];
        out_idx[(tok0 + t) * (long)KK + k0i + 1] = (float)tki[t][k0i + 1];
    }
}

extern "C" void kernel_launch(void* const* d_in, const int* in_sizes, int n_in,
                              void* d_out, int out_size, void* d_ws, size_t ws_size,
                              hipStream_t stream) {
    const float* x     = (const float*)d_in[0];
    const float* noise = (const float*)d_in[1];
    const float* Wl    = (const float*)d_in[2];
    const float* bl    = (const float*)d_in[3];
    const float* Wn    = (const float*)d_in[4];
    const float* bn    = (const float*)d_in[5];

    const int M = in_sizes[0] / DD;            // B*S = 32768
    float* out_router = (float*)d_out;
    float* out_idx    = (float*)d_out + (long)M * EE;
    ushort* wsB = (ushort*)d_ws;               // 1 MiB fragment-packed W hi/lo

    hipLaunchKernelGGL(prep_w, dim3(128), dim3(256), 0, stream, Wl, Wn, wsB);
    hipLaunchKernelGGL(router_main, dim3(M / TPB), dim3(NTH), 0, stream,
                       x, noise, wsB, Wl, bl, Wn, bn, out_router, out_idx);
}

// Round 9
// 373.587 us; speedup vs baseline: 1.2793x; 1.0019x over previous
//
#include <hip/hip_runtime.h>
#include <hip/hip_bf16.h>
#include <math.h>

namespace {
constexpr int DD = 2048;          // feature dim
constexpr int EE = 64;            // experts
constexpr int KK = 8;             // top-k
constexpr int TPB = 64;           // tokens per block
constexpr int BK = 32;            // K per step
constexpr int NTH = 256;          // 4 waves
constexpr int NSTEP = DD / BK;    // 64
constexpr int XB = TPB * BK * 4;  // 8192 B per x stage buffer (f32)
constexpr int WB = 16384;         // 16 KB W fragment slice per step
constexpr float TAU = 2e-4f;      // ambiguity gap threshold (>> split-bf16 error ~1e-5)
}

typedef __attribute__((ext_vector_type(8))) short short8;   // 8 bf16 (4 VGPRs)
typedef __attribute__((ext_vector_type(4))) float f32x4;

#define RES(t, e) res[(t) * 129 + (e)]

__device__ inline void split_bf16(float v, ushort& h, ushort& l) {
    __hip_bfloat16 hb = __float2bfloat16(v);
    float hf = __bfloat162float(hb);
    __hip_bfloat16 lb = __float2bfloat16(v - hf);
    h = __builtin_bit_cast(ushort, hb);
    l = __builtin_bit_cast(ushort, lb);
}

__device__ inline void conv_tile(const float4& A, const float4& B, short8& hi, short8& lo) {
    const float f[8] = {A.x, A.y, A.z, A.w, B.x, B.y, B.z, B.w};
#pragma unroll
    for (int i = 0; i < 8; ++i) {
        ushort h, l;
        split_bf16(f[i], h, l);
        hi[i] = (short)h;
        lo[i] = (short)l;
    }
}

__device__ inline void gload_lds16(const void* g, void* l) {
    __builtin_amdgcn_global_load_lds(
        (const __attribute__((address_space(1))) unsigned int*)g,
        (__attribute__((address_space(3))) unsigned int*)l,
        16, 0, 0);
}

// Pack W_linear||W_noise into MFMA B-fragment order (verified rounds 5-8):
// ushort layout [s32(64)][et(8)][hl(2)][lane(64)][i(8)]
// element: B[k][e] = W[e][k], e = et*16 + (lane&15), k = s32*32 + (lane>>4)*8 + i
__global__ __launch_bounds__(256)
void prep_w(const float* __restrict__ Wl, const float* __restrict__ Wn,
            ushort* __restrict__ wsB)
{
    const int t    = blockIdx.x * 256 + threadIdx.x;    // 0..32767
    const int lane = t & 63;
    const int et   = (t >> 6) & 7;
    const int s    = t >> 9;                            // 0..63
    const int e    = et * 16 + (lane & 15);
    const int k    = s * 32 + ((lane >> 4) * 8);
    const float* src = (e < EE) ? &Wl[(long)e * DD + k] : &Wn[(long)(e - EE) * DD + k];
    const float4 f0 = *reinterpret_cast<const float4*>(src);
    const float4 f1 = *reinterpret_cast<const float4*>(src + 4);
    const float f[8] = {f0.x, f0.y, f0.z, f0.w, f1.x, f1.y, f1.z, f1.w};
    uint hw[4], lw[4];
#pragma unroll
    for (int j = 0; j < 4; ++j) {
        ushort h0, l0, h1, l1;
        split_bf16(f[2 * j], h0, l0);
        split_bf16(f[2 * j + 1], h1, l1);
        hw[j] = (uint)h0 | ((uint)h1 << 16);
        lw[j] = (uint)l0 | ((uint)l1 << 16);
    }
    const size_t chunk = ((size_t)(s * 8 + et)) * 1024;   // ushort units per (s,et)
    *reinterpret_cast<uint4*>(&wsB[chunk + lane * 8])       = make_uint4(hw[0], hw[1], hw[2], hw[3]);
    *reinterpret_cast<uint4*>(&wsB[chunk + 512 + lane * 8]) = make_uint4(lw[0], lw[1], lw[2], lw[3]);
}

__global__ __launch_bounds__(NTH, 3)
void router_main(const float* __restrict__ x,
                 const float* __restrict__ noise,
                 const ushort* __restrict__ wsB,
                 const float* __restrict__ Wl, const float* __restrict__ bl,
                 const float* __restrict__ Wn, const float* __restrict__ bn,
                 float* __restrict__ out_router, float* __restrict__ out_idx)
{
    // [0,8K) xbuf0 | [8K,16K) xbuf1 | [16K,32K) wbuf0 | [32K,48K) wbuf1
    // post-loop: res[64][129] f32 aliases [0,33024); part/dots alias [33024,36096)
    __shared__ __align__(16) unsigned char smem[2 * XB + 2 * WB];
    __shared__ float tkv[TPB][KK];
    __shared__ int   tki[TPB][KK];
    __shared__ int   amb_list[TPB];
    __shared__ int   amb_count;

    const int tid  = threadIdx.x;
    const int lane = tid & 63;
    const int w    = tid >> 6;           // wave 0..3
    const int mh   = w >> 1;             // token half: rows mh*32..+31
    const int eq   = w & 1;              // et quad: et eq*4..+3
    const long tok0 = (long)blockIdx.x * TPB;
    if (tid == 0) amb_count = 0;

    // ---- staging source pointers (x pre-swizzled: unit ^= row&7; dest linear) ----
    const int srow  = tid >> 3;          // 0..31
    const int sunit = tid & 7;           // 16B unit within 128B row
    const float* gx0 = x + (tok0 + srow) * (long)DD + ((sunit ^ (srow & 7)) << 2);
    const float* gx1 = gx0 + 32 * (long)DD;            // rows 32..63, same xor (32%8==0)
    const char*  gw  = reinterpret_cast<const char*>(wsB);

    f32x4 acc[2][4];
#pragma unroll
    for (int mt = 0; mt < 2; ++mt)
#pragma unroll
        for (int e = 0; e < 4; ++e) acc[mt][e] = {0.f, 0.f, 0.f, 0.f};

    // ---- stage(s) into buffer c: 2 x-issues + 4 w-issues, all fire-and-forget ----
#define STAGE(s_, c_)                                                                   \
    do {                                                                                \
        unsigned char* xb_ = smem + (c_) * XB;                                          \
        unsigned char* wb_ = smem + 2 * XB + (c_) * WB;                                 \
        gload_lds16(gx0 + (s_) * BK, xb_ + w * 1024);                                   \
        gload_lds16(gx1 + (s_) * BK, xb_ + 4096 + w * 1024);                            \
        const char* ws_ = gw + (size_t)(s_) * WB;                                       \
        gload_lds16(ws_ + (size_t)(0 * 256 + tid) * 16, wb_ + 0 * 4096 + w * 1024);     \
        gload_lds16(ws_ + (size_t)(1 * 256 + tid) * 16, wb_ + 1 * 4096 + w * 1024);     \
        gload_lds16(ws_ + (size_t)(2 * 256 + tid) * 16, wb_ + 2 * 4096 + w * 1024);     \
        gload_lds16(ws_ + (size_t)(3 * 256 + tid) * 16, wb_ + 3 * 4096 + w * 1024);     \
    } while (0)

    // prologue
    STAGE(0, 0);
    __syncthreads();

    for (int s = 0; s < NSTEP; ++s) {
        const int cur = s & 1;
        if (s + 1 < NSTEP) STAGE(s + 1, cur ^ 1);   // issue next-step loads FIRST

        // ---- compute step s from buf[cur] ----
        const unsigned char* xb = smem + cur * XB;
        const unsigned char* wb = smem + 2 * XB + cur * WB;
        const int colr = lane & 15;
        const int krow = lane >> 4;                 // 0..3
        short8 ah[2], al[2];
#pragma unroll
        for (int mt = 0; mt < 2; ++mt) {
            const int r = mh * 32 + mt * 16 + colr;
            const unsigned char* base = xb + r * 128;
            const float4 f0 = *reinterpret_cast<const float4*>(
                base + (((krow * 2)     ^ (lane & 7)) * 16));
            const float4 f1 = *reinterpret_cast<const float4*>(
                base + (((krow * 2 + 1) ^ (lane & 7)) * 16));
            conv_tile(f0, f1, ah[mt], al[mt]);
        }
#pragma unroll
        for (int el = 0; el < 4; ++el) {
            const unsigned char* wbp = wb + (eq * 4 + el) * 2048 + lane * 16;
            const short8 bh  = *reinterpret_cast<const short8*>(wbp);
            const short8 bl2 = *reinterpret_cast<const short8*>(wbp + 1024);
            acc[0][el] = __builtin_amdgcn_mfma_f32_16x16x32_bf16(ah[0], bh,  acc[0][el], 0, 0, 0);
            acc[1][el] = __builtin_amdgcn_mfma_f32_16x16x32_bf16(ah[1], bh,  acc[1][el], 0, 0, 0);
            acc[0][el] = __builtin_amdgcn_mfma_f32_16x16x32_bf16(al[0], bh,  acc[0][el], 0, 0, 0);
            acc[1][el] = __builtin_amdgcn_mfma_f32_16x16x32_bf16(al[1], bh,  acc[1][el], 0, 0, 0);
            acc[0][el] = __builtin_amdgcn_mfma_f32_16x16x32_bf16(ah[0], bl2, acc[0][el], 0, 0, 0);
            acc[1][el] = __builtin_amdgcn_mfma_f32_16x16x32_bf16(ah[1], bl2, acc[1][el], 0, 0, 0);
        }
        __syncthreads();   // drains next-step loads (overlapped with compute above)
    }
#undef STAGE

    // ---------------- epilogue (res aliases dead stage buffers) ----------------
    float* res = reinterpret_cast<float*>(smem);   // [64][129]
    {
        // C/D layout (verified r5): col = lane&15 (expert), row = (lane>>4)*4 + reg
        const int col = lane & 15;
        const int rg  = (lane >> 4) * 4;
#pragma unroll
        for (int mt = 0; mt < 2; ++mt)
#pragma unroll
            for (int el = 0; el < 4; ++el) {
                const int e = (eq * 4 + el) * 16 + col;
                const float bias = (e < EE) ? bl[e] : bn[e - EE];
#pragma unroll
                for (int r = 0; r < 4; ++r)
                    RES(mh * 32 + mt * 16 + rg + r, e) = acc[mt][el][r] + bias;
            }
    }
    __syncthreads();

    // noisy = logits + noise * softplus(noise_logits)
    {
        const int t  = tid >> 2;
        const int e0 = (tid & 3) * 16;
        const float* nrow = &noise[(tok0 + t) * (long)EE];
#pragma unroll 4
        for (int j = 0; j < 16; ++j) {
            const int e = e0 + j;
            const float z  = RES(t, EE + e);
            const float sp = fmaxf(z, 0.f) + log1pf(expf(-fabsf(z)));
            RES(t, e) = RES(t, e) + nrow[e] * sp;
        }
    }
    __syncthreads();

    // top-9 extraction per token (threads 0..63); strict > keeps lowest index on ties
    if (tid < TPB) {
        const int t = tid;
        float lv[9]; int li[9];
#pragma unroll
        for (int k = 0; k < 9; ++k) {
            float best = -INFINITY;
            int bi = 0;
#pragma unroll 4
            for (int e = 0; e < EE; ++e) {
                const float v = RES(t, e);
                if (v > best) { best = v; bi = e; }
            }
            RES(t, bi) = -INFINITY;
            lv[k] = best; li[k] = bi;
        }
        bool amb = false;
#pragma unroll
        for (int k = 0; k < 8; ++k) amb |= (lv[k] - lv[k + 1] < TAU);
        const float m = lv[0];
        float p[KK];
        float sm = 0.f;
#pragma unroll
        for (int k = 0; k < KK; ++k) { p[k] = expf(lv[k] - m); sm += p[k]; }
        const float inv = 1.f / sm;
#pragma unroll
        for (int k = 0; k < KK; ++k) { tkv[t][k] = p[k] * inv; tki[t][k] = li[k]; }
        if (amb) { const int pos = atomicAdd(&amb_count, 1); amb_list[pos] = t; }
    }
    __syncthreads();

    // fp64 recompute of ambiguous tokens (near-tie -> split-bf16 ordering unsafe)
    const int namb = amb_count;
    double* part = reinterpret_cast<double*>(smem + 33024);   // 256 doubles
    double* dots = reinterpret_cast<double*>(smem + 35072);   // 128 doubles
    for (int a = 0; a < namb; ++a) {
        const int t = amb_list[a];
        {
            const int e  = tid >> 1;
            const int kb = (tid & 1) * (DD / 2);
            const float* xr = &x[(tok0 + t) * (long)DD + kb];
            const float* wr = (e < EE) ? &Wl[(long)e * DD + kb]
                                       : &Wn[(long)(e - EE) * DD + kb];
            double a2 = 0.0;
            for (int k = 0; k < DD / 2; k += 8) {   // 8-deep: 4 loads in flight
                const float4 xv0 = *reinterpret_cast<const float4*>(&xr[k]);
                const float4 wv0 = *reinterpret_cast<const float4*>(&wr[k]);
                const float4 xv1 = *reinterpret_cast<const float4*>(&xr[k + 4]);
                const float4 wv1 = *reinterpret_cast<const float4*>(&wr[k + 4]);
                a2 = fma((double)xv0.x, (double)wv0.x, a2);
                a2 = fma((double)xv0.y, (double)wv0.y, a2);
                a2 = fma((double)xv0.z, (double)wv0.z, a2);
                a2 = fma((double)xv0.w, (double)wv0.w, a2);
                a2 = fma((double)xv1.x, (double)wv1.x, a2);
                a2 = fma((double)xv1.y, (double)wv1.y, a2);
                a2 = fma((double)xv1.z, (double)wv1.z, a2);
                a2 = fma((double)xv1.w, (double)wv1.w, a2);
            }
            part[tid] = a2;
        }
        __syncthreads();
        if (tid < 128) dots[tid] = part[2 * tid] + part[2 * tid + 1];
        __syncthreads();
        if (tid < EE) {   // wave 0: fp64 noisy + butterfly top-8 + fp64 softmax
            const double v  = dots[tid] + (double)bl[tid];
            const double z  = dots[EE + tid] + (double)bn[tid];
            const double sp = fmax(z, 0.0) + log1p(exp(-fabs(z)));
            double val = v + (double)noise[(tok0 + t) * (long)EE + tid] * sp;
            int    idx = tid;
            double sel[KK]; int sidx[KK];
#pragma unroll
            for (int k = 0; k < KK; ++k) {
                double mv = val; int mi = idx;
#pragma unroll
                for (int m = 1; m < 64; m <<= 1) {
                    const double ov = __shfl_xor(mv, m, 64);
                    const int    oi = __shfl_xor(mi, m, 64);
                    if (ov > mv || (ov == mv && oi < mi)) { mv = ov; mi = oi; }
                }
                sel[k] = mv; sidx[k] = mi;
                if (idx == mi) val = -INFINITY;
            }
            if (tid == 0) {
                const double mx = sel[0];
                double p[KK]; double sm = 0.0;
#pragma unroll
                for (int k = 0; k < KK; ++k) { p[k] = exp(sel[k] - mx); sm += p[k]; }
                const double inv = 1.0 / sm;
#pragma unroll
                for (int k = 0; k < KK; ++k) {
                    tkv[t][k] = (float)(p[k] * inv);
                    tki[t][k] = sidx[k];
                }
            }
        }
        __syncthreads();
    }

    // router output: compare-select scatter, coalesced float4 stores
    {
        const int t  = tid >> 2;
        const int e0 = (tid & 3) * 16;
        int   ki[KK];
        float kv[KK];
#pragma unroll
        for (int k = 0; k < KK; ++k) { ki[k] = tki[t][k]; kv[k] = tkv[t][k]; }
        float4 v[4];
        float* vf = reinterpret_cast<float*>(v);
#pragma unroll
        for (int j = 0; j < 16; ++j) {
            float val = 0.f;
#pragma unroll
            for (int k = 0; k < KK; ++k)
                val = (ki[k] == e0 + j) ? kv[k] : val;
            vf[j] = val;
        }
        float4* dst = reinterpret_cast<float4*>(&out_router[(tok0 + t) * (long)EE + e0]);
#pragma unroll
        for (int q = 0; q < 4; ++q) dst[q] = v[q];
    }
    // indices output, written as float32 values (whole d_out read as f32 by harness)
    {
        const int f = tid * 2;
        const int t = f >> 3;
        const int k0i = f & 7;
        out_idx[(tok0 + t) * (long)KK + k0i]     = (float)tki[t][k0i];
        out_idx[(tok0 + t) * (long)KK + k0i + 1] = (float)tki[t][k0i + 1];
    }
}

extern "C" void kernel_launch(void* const* d_in, const int* in_sizes, int n_in,
                              void* d_out, int out_size, void* d_ws, size_t ws_size,
                              hipStream_t stream) {
    const float* x     = (const float*)d_in[0];
    const float* noise = (const float*)d_in[1];
    const float* Wl    = (const float*)d_in[2];
    const float* bl    = (const float*)d_in[3];
    const float* Wn    = (const float*)d_in[4];
    const float* bn    = (const float*)d_in[5];

    const int M = in_sizes[0] / DD;            // B*S = 32768
    float* out_router = (float*)d_out;
    float* out_idx    = (float*)d_out + (long)M * EE;
    ushort* wsB = (ushort*)d_ws;               // 1 MiB fragment-packed W hi/lo

    hipLaunchKernelGGL(prep_w, dim3(128), dim3(256), 0, stream, Wl, Wn, wsB);
    hipLaunchKernelGGL(router_main, dim3(M / TPB), dim3(NTH), 0, stream,
                       x, noise, wsB, Wl, bl, Wn, bn, out_router, out_idx);
}